// Round 4
// baseline (3816.581 us; speedup 1.0000x reference)
//
#include <hip/hip_runtime.h>

// SimpleLSTM B=128,T=8192,H=96. R17: fold y into gate wave 0; delete the
// 5th wave. R16 post-mortem: SIMD0's extra MFMAs were never the straggler;
// step = read(120) + MFMA pipe(349, irreducible: 72 MFMAs/CU-step for the
// 384x96 GEMV) + drain(40) + act(90) + barrier(~100) + post-barrier LDS
// queue (15 b128 across 5 waves). Key insight: y_t = w_out . h_t and h_t IS
// the B-operand every gate wave loads at step t+1 -- so wave 0 computes y
// from its own b0/b1/b2 frags (R16's validated 24-fma + 2-shfl VALU dot)
// with ZERO extra LDS reads, hidden under its own 349-cyc MFMA pipe time.
// Deleting the y-wave cuts the post-barrier burst 15->12 b128, barrier
// 5->4 waves, SIMD0 issue contention gone; no wave's chain grows. Ring
// flush -> wave 1. setprio dropped (no role asymmetry left). Carried: 2
// batches in B cols, 4 waves x 6 tiles, permuted W rows, exp2 prescale,
// named scalars, pinned A-frags, x register prefetch, unroll 2, depth-3
// select, all-lane h write, y ring flush by 128.

#define T_LEN 8192
#define H_DIM 96
#define NTHR  256   // 4 waves, one batch-pair per block
#define CHUNK 128
#define LOG2E 1.44269504f

typedef float    f32x4 __attribute__((ext_vector_type(4)));
typedef _Float16 half8 __attribute__((ext_vector_type(8)));

#define MFMA16(A, B, C)                                                        \
    __builtin_amdgcn_mfma_f32_16x16x32_f16(__builtin_bit_cast(half8, (A)),     \
                                           __builtin_bit_cast(half8, (B)),     \
                                           (C), 0, 0, 0)

__device__ __forceinline__ float sig2(float s) {   // sigmoid, s = log2e*pre
    return __builtin_amdgcn_rcpf(1.0f + __builtin_amdgcn_exp2f(-s));
}
__device__ __forceinline__ float tanh2(float sg) { // tanh, sg = 2log2e*pre
    return 1.0f - 2.0f * __builtin_amdgcn_rcpf(1.0f + __builtin_amdgcn_exp2f(sg));
}

__device__ __forceinline__ f32x4 load_afrag(const float* __restrict__ w_hh,
                                            int mt, int kt, int m, int quad) {
    half8 f;
    const int r = m & 3;                       // gate: 0=i 1=f 2=g 3=o
    const float scale = (r == 2) ? 2.0f * LOG2E : LOG2E;
    const int orig = r * 96 + 4 * mt + (m >> 2);
    const float* src = w_hh + orig * H_DIM + kt * 32 + quad * 8;
    #pragma unroll
    for (int jj = 0; jj < 8; ++jj) f[jj] = (_Float16)(scale * src[jj]);
    return __builtin_bit_cast(f32x4, f);
}

__global__ __launch_bounds__(NTHR, 2) void lstm_mfma17_kernel(
    const float* __restrict__ x,      // [B, T]
    const float* __restrict__ w_ih,   // [4H]
    const float* __restrict__ w_hh,   // [4H, H]
    const float* __restrict__ b_ih,   // [4H]
    const float* __restrict__ b_hh,   // [4H]
    const float* __restrict__ w_out,  // [H]
    const float* __restrict__ b_out,  // [1]
    float* __restrict__ y)            // [B, T]
{
    const int tid  = threadIdx.x;
    const int wv   = tid >> 6;        // wave 0..3, all gate waves
    const int lane = tid & 63;
    const int m    = lane & 15;       // A-row / D-column index
    const int quad = lane >> 4;       // D row group / B K-chunk
    const int cc   = m & 7;           // within-batch column
    const int bsub = m >> 3;          // 0: batch 2b, 1: batch 2b+1

    __shared__ __align__(16) _Float16 h_s[2][2][H_DIM];       // [buf][bsub][cell]
    __shared__ __align__(16) float    y_buf[2][2][CHUNK];     // [bsub][ring][i]
    __shared__ __align__(16) float    x_s[2][T_LEN + 8];      // +8 pad

    // ---- stage both batches' x into LDS
    {
        const float* xpair = x + (size_t)(2 * blockIdx.x) * T_LEN;
        for (int i = tid * 4; i < T_LEN; i += NTHR * 4) {
            *reinterpret_cast<f32x4*>(&x_s[0][i]) =
                *reinterpret_cast<const f32x4*>(&xpair[i]);
            *reinterpret_cast<f32x4*>(&x_s[1][i]) =
                *reinterpret_cast<const f32x4*>(&xpair[T_LEN + i]);
        }
    }

    // ---- A fragments (named, pinned). Wave wv owns tiles 6wv..6wv+5.
    const int mt0 = 6 * wv;
    f32x4 af00 = load_afrag(w_hh, mt0 + 0, 0, m, quad);
    f32x4 af01 = load_afrag(w_hh, mt0 + 0, 1, m, quad);
    f32x4 af02 = load_afrag(w_hh, mt0 + 0, 2, m, quad);
    f32x4 af10 = load_afrag(w_hh, mt0 + 1, 0, m, quad);
    f32x4 af11 = load_afrag(w_hh, mt0 + 1, 1, m, quad);
    f32x4 af12 = load_afrag(w_hh, mt0 + 1, 2, m, quad);
    f32x4 af20 = load_afrag(w_hh, mt0 + 2, 0, m, quad);
    f32x4 af21 = load_afrag(w_hh, mt0 + 2, 1, m, quad);
    f32x4 af22 = load_afrag(w_hh, mt0 + 2, 2, m, quad);
    f32x4 af30 = load_afrag(w_hh, mt0 + 3, 0, m, quad);
    f32x4 af31 = load_afrag(w_hh, mt0 + 3, 1, m, quad);
    f32x4 af32 = load_afrag(w_hh, mt0 + 3, 2, m, quad);
    f32x4 af40 = load_afrag(w_hh, mt0 + 4, 0, m, quad);
    f32x4 af41 = load_afrag(w_hh, mt0 + 4, 1, m, quad);
    f32x4 af42 = load_afrag(w_hh, mt0 + 4, 2, m, quad);
    f32x4 af50 = load_afrag(w_hh, mt0 + 5, 0, m, quad);
    f32x4 af51 = load_afrag(w_hh, mt0 + 5, 1, m, quad);
    f32x4 af52 = load_afrag(w_hh, mt0 + 5, 2, m, quad);
    f32x4 zero4 = {0.f, 0.f, 0.f, 0.f};
    asm volatile("" : "+v"(af00), "+v"(af01), "+v"(af02), "+v"(af10),
                      "+v"(af11), "+v"(af12), "+v"(af20));
    asm volatile("" : "+v"(af21), "+v"(af22), "+v"(af30), "+v"(af31),
                      "+v"(af32), "+v"(af40), "+v"(af41));
    asm volatile("" : "+v"(af42), "+v"(af50), "+v"(af51), "+v"(af52),
                      "+v"(zero4));

    // ---- wave 0 only: w_out slices matching the B-frag k-positions
    f32x4 woa0 = {0,0,0,0}, woa1 = {0,0,0,0}, wob0 = {0,0,0,0},
          wob1 = {0,0,0,0}, woc0 = {0,0,0,0}, woc1 = {0,0,0,0};
    if (wv == 0) {
        woa0 = *reinterpret_cast<const f32x4*>(&w_out[quad * 8]);
        woa1 = *reinterpret_cast<const f32x4*>(&w_out[quad * 8 + 4]);
        wob0 = *reinterpret_cast<const f32x4*>(&w_out[32 + quad * 8]);
        wob1 = *reinterpret_cast<const f32x4*>(&w_out[32 + quad * 8 + 4]);
        woc0 = *reinterpret_cast<const f32x4*>(&w_out[64 + quad * 8]);
        woc1 = *reinterpret_cast<const f32x4*>(&w_out[64 + quad * 8 + 4]);
    }
    asm volatile("" : "+v"(woa0), "+v"(woa1), "+v"(wob0), "+v"(wob1),
                      "+v"(woc0), "+v"(woc1));

    // ---- per-lane cell params (exp2-domain prescaled)
    const int sel  = (cc >= 6) ? (cc - 6) : cc;
    const int cell = 24 * wv + 4 * sel + quad;
    const bool s_b0 = sel & 1;
    const bool s_b1 = (sel >> 1) & 1;
    const bool s_b2 = (sel >> 2) & 1;
    const float bias_i = LOG2E * (b_ih[0 * H_DIM + cell] + b_hh[0 * H_DIM + cell]);
    const float bias_f = LOG2E * (b_ih[1 * H_DIM + cell] + b_hh[1 * H_DIM + cell]);
    const float bias_g = 2.0f * LOG2E * (b_ih[2 * H_DIM + cell] + b_hh[2 * H_DIM + cell]);
    const float bias_o = LOG2E * (b_ih[3 * H_DIM + cell] + b_hh[3 * H_DIM + cell]);
    const float wih_i  = LOG2E * w_ih[0 * H_DIM + cell];
    const float wih_f  = LOG2E * w_ih[1 * H_DIM + cell];
    const float wih_g  = 2.0f * LOG2E * w_ih[2 * H_DIM + cell];
    const float wih_o  = LOG2E * w_ih[3 * H_DIM + cell];
    const float bout   = b_out[0];
    float c = 0.f;
    if (tid < 2 * H_DIM) (&h_s[0][0][0])[tid] = (_Float16)0.0f;  // buf 0
    __syncthreads();

    float x_cur_next = x_s[bsub][0];  // register prefetch of x[it] (own batch)

    // iter it: waves read h_{it-1} (h_s[it&1]) and produce h_it; wave 0
    // additionally computes y_{it-1} = w_out . h_{it-1} from its own B-frags.
    #pragma unroll 2
    for (int it = 0; it <= T_LEN + 1; ++it) {
        const int p = it & 1;
        // wave 0 reads one extra iter (it==T_LEN) to produce y_{T-1}
        const bool rd = (it < T_LEN) || (wv == 0 && it == T_LEN);

        f32x4 b0, b1, b2;
        const float x_cur = x_cur_next;
        if (rd) {
            b0 = *reinterpret_cast<const f32x4*>(&h_s[p][bsub][quad * 8]);
            b1 = *reinterpret_cast<const f32x4*>(&h_s[p][bsub][32 + quad * 8]);
            b2 = *reinterpret_cast<const f32x4*>(&h_s[p][bsub][64 + quad * 8]);
            x_cur_next = x_s[bsub][it + 1];  // pad absorbs over-read
        }

        if (it < T_LEN) {
            f32x4 acc0 = MFMA16(af00, b0, zero4);
            f32x4 acc1 = MFMA16(af10, b0, zero4);
            f32x4 acc2 = MFMA16(af20, b0, zero4);
            f32x4 acc3 = MFMA16(af30, b0, zero4);
            f32x4 acc4 = MFMA16(af40, b0, zero4);
            f32x4 acc5 = MFMA16(af50, b0, zero4);
            acc0 = MFMA16(af01, b1, acc0);
            acc1 = MFMA16(af11, b1, acc1);
            acc2 = MFMA16(af21, b1, acc2);
            acc3 = MFMA16(af31, b1, acc3);
            acc4 = MFMA16(af41, b1, acc4);
            acc5 = MFMA16(af51, b1, acc5);
            acc0 = MFMA16(af02, b2, acc0);
            acc1 = MFMA16(af12, b2, acc1);
            acc2 = MFMA16(af22, b2, acc2);
            acc3 = MFMA16(af32, b2, acc3);
            acc4 = MFMA16(af42, b2, acc4);
            acc5 = MFMA16(af52, b2, acc5);

            // depth-3 binary select
            const f32x4 t0 = s_b0 ? acc1 : acc0;
            const f32x4 t1 = s_b0 ? acc3 : acc2;
            const f32x4 t2 = s_b0 ? acc5 : acc4;
            const f32x4 g4 = s_b2 ? t2 : (s_b1 ? t1 : t0);

            const float s0 = g4.x + fmaf(x_cur, wih_i, bias_i);
            const float s1 = g4.y + fmaf(x_cur, wih_f, bias_f);
            const float s2 = g4.z + fmaf(x_cur, wih_g, bias_g);
            const float s3 = g4.w + fmaf(x_cur, wih_o, bias_o);
            const float ig = sig2(s0);
            const float fg = sig2(s1);
            const float gg = tanh2(s2);
            const float og = sig2(s3);
            c = fmaf(fg, c, ig * gg);
            const float h = og * tanh2(2.0f * LOG2E * c);
            // all 64 lanes write; cc=6,7 bitwise-duplicate cc=0,1 (benign)
            h_s[p ^ 1][bsub][cell] = (_Float16)h;
        }

        // ---- wave 0: y_{it-1} = w_out . h_{it-1} from its own B-frags
        // (VALU only; no extra LDS reads; hidden under the MFMA pipe time)
        if (wv == 0 && rd && it > 0) {
            const half8 hb0 = __builtin_bit_cast(half8, b0);
            const half8 hb1 = __builtin_bit_cast(half8, b1);
            const half8 hb2 = __builtin_bit_cast(half8, b2);
            float a0 = 0.f, a1 = 0.f, a2 = 0.f;   // 3 parallel chains
            a0 = fmaf((float)hb0[0], woa0.x, a0);
            a1 = fmaf((float)hb1[0], wob0.x, a1);
            a2 = fmaf((float)hb2[0], woc0.x, a2);
            a0 = fmaf((float)hb0[1], woa0.y, a0);
            a1 = fmaf((float)hb1[1], wob0.y, a1);
            a2 = fmaf((float)hb2[1], woc0.y, a2);
            a0 = fmaf((float)hb0[2], woa0.z, a0);
            a1 = fmaf((float)hb1[2], wob0.z, a1);
            a2 = fmaf((float)hb2[2], woc0.z, a2);
            a0 = fmaf((float)hb0[3], woa0.w, a0);
            a1 = fmaf((float)hb1[3], wob0.w, a1);
            a2 = fmaf((float)hb2[3], woc0.w, a2);
            a0 = fmaf((float)hb0[4], woa1.x, a0);
            a1 = fmaf((float)hb1[4], wob1.x, a1);
            a2 = fmaf((float)hb2[4], woc1.x, a2);
            a0 = fmaf((float)hb0[5], woa1.y, a0);
            a1 = fmaf((float)hb1[5], wob1.y, a1);
            a2 = fmaf((float)hb2[5], woc1.y, a2);
            a0 = fmaf((float)hb0[6], woa1.z, a0);
            a1 = fmaf((float)hb1[6], wob1.z, a1);
            a2 = fmaf((float)hb2[6], woc1.z, a2);
            a0 = fmaf((float)hb0[7], woa1.w, a0);
            a1 = fmaf((float)hb1[7], wob1.w, a1);
            a2 = fmaf((float)hb2[7], woc1.w, a2);
            float acc = a0 + a1 + a2;             // this lane's 24 terms
            acc += __shfl_xor(acc, 32, 64);       // quad ^2
            acc += __shfl_xor(acc, 16, 64);       // quad ^1 -> full dot
            if (lane == 0 || lane == 8)           // (bsub 0/1, quad 0, cc 0)
                y_buf[bsub][((it - 1) >> 7) & 1][(it - 1) & (CHUNK - 1)] =
                    acc + bout;
        }

        // ---- wave 1: ring flush, chunk [it-1-CHUNK, it-1) complete
        if (wv == 1 && (it & (CHUNK - 1)) == 1 && it > 1) {
            const int base = it - 1 - CHUNK;
            const int pb   = (base >> 7) & 1;
            const int bsel = lane >> 5;
            const int li   = lane & 31;
            const f32x4 v =
                *reinterpret_cast<const f32x4*>(&y_buf[bsel][pb][li * 4]);
            float* yrow = y + (size_t)(2 * blockIdx.x + bsel) * T_LEN;
            *reinterpret_cast<f32x4*>(&yrow[base + li * 4]) = v;
        }

        __syncthreads();  // h_s[p^1] + y_buf ready (4-wave barrier)
    }
}

extern "C" void kernel_launch(void* const* d_in, const int* in_sizes, int n_in,
                              void* d_out, int out_size, void* d_ws, size_t ws_size,
                              hipStream_t stream) {
    const float* x     = (const float*)d_in[0];
    const float* w_ih  = (const float*)d_in[1];
    const float* w_hh  = (const float*)d_in[2];
    const float* b_ih  = (const float*)d_in[3];
    const float* b_hh  = (const float*)d_in[4];
    const float* w_out = (const float*)d_in[5];
    const float* b_out = (const float*)d_in[6];
    float* y = (float*)d_out;

    const int NBLK = 64;  // 2 batches per block (packed into B columns)
    lstm_mfma17_kernel<<<dim3(NBLK), dim3(NTHR), 0, stream>>>(
        x, w_ih, w_hh, b_ih, b_hh, w_out, b_out, y);
}

// Round 5
// 3552.692 us; speedup vs baseline: 1.0743x; 1.0743x over previous
//
#include <hip/hip_runtime.h>

// SimpleLSTM B=128,T=8192,H=96. R18: split gate waves 4x18-MFMA -> 8x9-MFMA.
// R17 post-mortem (2x confirmed): work added to a gate wave's pre-barrier
// chain costs ~1:1 -- only a DIFFERENT wave can hide it. Floor model: per-
// SIMD matrix pipe = 18 MFMA x 19.4 = 349 cyc/step (72 MFMA/CU is the f16
// instruction floor for the 384x96 weights); R15's 895-cyc step = 349 pipe
// + ~546 serial overhead (ds_read ~120 + drain + activation ~90 + barrier
// ~100 + skew) fully exposed because each SIMD ran ONE gate wave. R18 puts
// TWO 9-MFMA gate waves per SIMD (same 18 MFMA/SIMD pipe floor): wave A's
// read-latency/activation/barrier-arrive overlaps wave B's MFMA issue.
// NOT R13's regime (that was 2x18=36 MFMA/SIMD = 700 pipe). 9th wave =
// R15/R16's dedicated y+flush wave (VALU dot, no matrix-pipe ops).
// Carried: 2 batches in B cols, permuted W rows, exp2 prescale, named
// scalars, pinned A-frags, x register prefetch, unroll 2, all-lane h write,
// y ring flush by 128, setprio(1) on gate waves (role-split vs y-wave).

#define T_LEN 8192
#define H_DIM 96
#define NTHR  576   // 9 waves: 8 gate waves (3 tiles each) + 1 y/flush wave
#define CHUNK 128
#define LOG2E 1.44269504f

typedef float    f32x4 __attribute__((ext_vector_type(4)));
typedef _Float16 half8 __attribute__((ext_vector_type(8)));

#define MFMA16(A, B, C)                                                        \
    __builtin_amdgcn_mfma_f32_16x16x32_f16(__builtin_bit_cast(half8, (A)),     \
                                           __builtin_bit_cast(half8, (B)),     \
                                           (C), 0, 0, 0)

__device__ __forceinline__ float sig2(float s) {   // sigmoid, s = log2e*pre
    return __builtin_amdgcn_rcpf(1.0f + __builtin_amdgcn_exp2f(-s));
}
__device__ __forceinline__ float tanh2(float sg) { // tanh, sg = 2log2e*pre
    return 1.0f - 2.0f * __builtin_amdgcn_rcpf(1.0f + __builtin_amdgcn_exp2f(sg));
}

__device__ __forceinline__ f32x4 load_afrag(const float* __restrict__ w_hh,
                                            int mt, int kt, int m, int quad) {
    half8 f;
    const int r = m & 3;                       // gate: 0=i 1=f 2=g 3=o
    const float scale = (r == 2) ? 2.0f * LOG2E : LOG2E;
    const int orig = r * 96 + 4 * mt + (m >> 2);
    const float* src = w_hh + orig * H_DIM + kt * 32 + quad * 8;
    #pragma unroll
    for (int jj = 0; jj < 8; ++jj) f[jj] = (_Float16)(scale * src[jj]);
    return __builtin_bit_cast(f32x4, f);
}

__global__ __launch_bounds__(NTHR, 1) void lstm_mfma18_kernel(
    const float* __restrict__ x,      // [B, T]
    const float* __restrict__ w_ih,   // [4H]
    const float* __restrict__ w_hh,   // [4H, H]
    const float* __restrict__ b_ih,   // [4H]
    const float* __restrict__ b_hh,   // [4H]
    const float* __restrict__ w_out,  // [H]
    const float* __restrict__ b_out,  // [1]
    float* __restrict__ y)            // [B, T]
{
    const int tid  = threadIdx.x;
    const int wv   = tid >> 6;        // 0..7 = gate waves, 8 = y/flush
    const int lane = tid & 63;
    const int m    = lane & 15;       // A-row / D-column index
    const int quad = lane >> 4;       // D row group / B K-chunk
    const int cc   = m & 7;           // within-batch column
    const int bsub = m >> 3;          // 0: batch 2b, 1: batch 2b+1

    __shared__ __align__(16) _Float16 h_s[2][2][H_DIM];       // [buf][bsub][cell]
    __shared__ __align__(16) float    y_buf[2][2][CHUNK];     // [bsub][ring][i]
    __shared__ __align__(16) float    x_s[2][T_LEN + 8];      // +8 pad

    // ---- stage both batches' x into LDS
    {
        const float* xpair = x + (size_t)(2 * blockIdx.x) * T_LEN;
        for (int i = tid * 4; i < T_LEN; i += NTHR * 4) {
            *reinterpret_cast<f32x4*>(&x_s[0][i]) =
                *reinterpret_cast<const f32x4*>(&xpair[i]);
            *reinterpret_cast<f32x4*>(&x_s[1][i]) =
                *reinterpret_cast<const f32x4*>(&xpair[T_LEN + i]);
        }
    }

    // ---- A fragments (named, pinned). Gate wave wv owns tiles 3wv..3wv+2.
    // y-wave loads wave-0 duplicates (no OOB, unused).
    const int mt0 = (wv < 8) ? 3 * wv : 0;
    f32x4 af00 = load_afrag(w_hh, mt0 + 0, 0, m, quad);
    f32x4 af01 = load_afrag(w_hh, mt0 + 0, 1, m, quad);
    f32x4 af02 = load_afrag(w_hh, mt0 + 0, 2, m, quad);
    f32x4 af10 = load_afrag(w_hh, mt0 + 1, 0, m, quad);
    f32x4 af11 = load_afrag(w_hh, mt0 + 1, 1, m, quad);
    f32x4 af12 = load_afrag(w_hh, mt0 + 1, 2, m, quad);
    f32x4 af20 = load_afrag(w_hh, mt0 + 2, 0, m, quad);
    f32x4 af21 = load_afrag(w_hh, mt0 + 2, 1, m, quad);
    f32x4 af22 = load_afrag(w_hh, mt0 + 2, 2, m, quad);
    f32x4 zero4 = {0.f, 0.f, 0.f, 0.f};
    asm volatile("" : "+v"(af00), "+v"(af01), "+v"(af02), "+v"(af10),
                      "+v"(af11), "+v"(af12), "+v"(af20));
    asm volatile("" : "+v"(af21), "+v"(af22), "+v"(zero4));

    // ---- y-wave only: w_out slices matching the B-frag k-positions (f32)
    f32x4 woa0 = {0,0,0,0}, woa1 = {0,0,0,0}, wob0 = {0,0,0,0},
          wob1 = {0,0,0,0}, woc0 = {0,0,0,0}, woc1 = {0,0,0,0};
    if (wv == 8) {
        woa0 = *reinterpret_cast<const f32x4*>(&w_out[quad * 8]);
        woa1 = *reinterpret_cast<const f32x4*>(&w_out[quad * 8 + 4]);
        wob0 = *reinterpret_cast<const f32x4*>(&w_out[32 + quad * 8]);
        wob1 = *reinterpret_cast<const f32x4*>(&w_out[32 + quad * 8 + 4]);
        woc0 = *reinterpret_cast<const f32x4*>(&w_out[64 + quad * 8]);
        woc1 = *reinterpret_cast<const f32x4*>(&w_out[64 + quad * 8 + 4]);
    }

    // ---- per-lane cell params (gate waves; exp2-domain prescaled)
    const int sel  = (cc < 3) ? cc : ((cc < 6) ? (cc - 3) : (cc - 6));
    const int cell = (wv < 8) ? (12 * wv + 4 * sel + quad) : 0;
    const bool s_is1 = (sel == 1);
    const bool s_is2 = (sel == 2);
    const float bias_i = LOG2E * (b_ih[0 * H_DIM + cell] + b_hh[0 * H_DIM + cell]);
    const float bias_f = LOG2E * (b_ih[1 * H_DIM + cell] + b_hh[1 * H_DIM + cell]);
    const float bias_g = 2.0f * LOG2E * (b_ih[2 * H_DIM + cell] + b_hh[2 * H_DIM + cell]);
    const float bias_o = LOG2E * (b_ih[3 * H_DIM + cell] + b_hh[3 * H_DIM + cell]);
    const float wih_i  = LOG2E * w_ih[0 * H_DIM + cell];
    const float wih_f  = LOG2E * w_ih[1 * H_DIM + cell];
    const float wih_g  = 2.0f * LOG2E * w_ih[2 * H_DIM + cell];
    const float wih_o  = LOG2E * w_ih[3 * H_DIM + cell];
    const float bout   = b_out[0];
    float c = 0.f;
    if (tid < 2 * H_DIM) (&h_s[0][0][0])[tid] = (_Float16)0.0f;  // buf 0
    __syncthreads();

    if (wv < 8) __builtin_amdgcn_s_setprio(1);  // gates win SIMD arbitration

    float x_cur_next = x_s[bsub][0];  // register prefetch of x[it] (own batch)

    // iter it: gate waves read h_{it-1} (h_s[it&1]) and produce h_it;
    // y-wave reads the same buffer, stores y_{it-1}, flushes the ring.
    #pragma unroll 2
    for (int it = 0; it <= T_LEN + 1; ++it) {
        const int p = it & 1;

        if (wv < 8) {
            // ------------- gate wave (3 tiles, 9 MFMAs) -------------
            if (it < T_LEN) {
                const f32x4 b0 = *reinterpret_cast<const f32x4*>(&h_s[p][bsub][quad * 8]);
                const f32x4 b1 = *reinterpret_cast<const f32x4*>(&h_s[p][bsub][32 + quad * 8]);
                const f32x4 b2 = *reinterpret_cast<const f32x4*>(&h_s[p][bsub][64 + quad * 8]);
                const float x_cur = x_cur_next;
                x_cur_next = x_s[bsub][it + 1];  // pad absorbs over-read

                f32x4 acc0 = MFMA16(af00, b0, zero4);
                f32x4 acc1 = MFMA16(af10, b0, zero4);
                f32x4 acc2 = MFMA16(af20, b0, zero4);
                acc0 = MFMA16(af01, b1, acc0);
                acc1 = MFMA16(af11, b1, acc1);
                acc2 = MFMA16(af21, b1, acc2);
                acc0 = MFMA16(af02, b2, acc0);
                acc1 = MFMA16(af12, b2, acc1);
                acc2 = MFMA16(af22, b2, acc2);

                // depth-2 select among 3 accs
                const f32x4 t0 = s_is1 ? acc1 : acc0;
                const f32x4 g4 = s_is2 ? acc2 : t0;

                const float s0 = g4.x + fmaf(x_cur, wih_i, bias_i);
                const float s1 = g4.y + fmaf(x_cur, wih_f, bias_f);
                const float s2 = g4.z + fmaf(x_cur, wih_g, bias_g);
                const float s3 = g4.w + fmaf(x_cur, wih_o, bias_o);
                const float ig = sig2(s0);
                const float fg = sig2(s1);
                const float gg = tanh2(s2);
                const float og = sig2(s3);
                c = fmaf(fg, c, ig * gg);
                const float h = og * tanh2(2.0f * LOG2E * c);
                // all lanes write; cc 3..7 bitwise-duplicate cc 0..2 (benign)
                h_s[p ^ 1][bsub][cell] = (_Float16)h;
            }
        } else {
            // ------------- y / flush wave (VALU only) -------------
            if (it <= T_LEN) {
                const f32x4 b0 = *reinterpret_cast<const f32x4*>(&h_s[p][bsub][quad * 8]);
                const f32x4 b1 = *reinterpret_cast<const f32x4*>(&h_s[p][bsub][32 + quad * 8]);
                const f32x4 b2 = *reinterpret_cast<const f32x4*>(&h_s[p][bsub][64 + quad * 8]);
                const half8 hb0 = __builtin_bit_cast(half8, b0);
                const half8 hb1 = __builtin_bit_cast(half8, b1);
                const half8 hb2 = __builtin_bit_cast(half8, b2);
                float a0 = 0.f, a1 = 0.f, a2 = 0.f;   // 3 parallel chains
                a0 = fmaf((float)hb0[0], woa0.x, a0);
                a1 = fmaf((float)hb1[0], wob0.x, a1);
                a2 = fmaf((float)hb2[0], woc0.x, a2);
                a0 = fmaf((float)hb0[1], woa0.y, a0);
                a1 = fmaf((float)hb1[1], wob0.y, a1);
                a2 = fmaf((float)hb2[1], woc0.y, a2);
                a0 = fmaf((float)hb0[2], woa0.z, a0);
                a1 = fmaf((float)hb1[2], wob0.z, a1);
                a2 = fmaf((float)hb2[2], woc0.z, a2);
                a0 = fmaf((float)hb0[3], woa0.w, a0);
                a1 = fmaf((float)hb1[3], wob0.w, a1);
                a2 = fmaf((float)hb2[3], woc0.w, a2);
                a0 = fmaf((float)hb0[4], woa1.x, a0);
                a1 = fmaf((float)hb1[4], wob1.x, a1);
                a2 = fmaf((float)hb2[4], woc1.x, a2);
                a0 = fmaf((float)hb0[5], woa1.y, a0);
                a1 = fmaf((float)hb1[5], wob1.y, a1);
                a2 = fmaf((float)hb2[5], woc1.y, a2);
                a0 = fmaf((float)hb0[6], woa1.z, a0);
                a1 = fmaf((float)hb1[6], wob1.z, a1);
                a2 = fmaf((float)hb2[6], woc1.z, a2);
                a0 = fmaf((float)hb0[7], woa1.w, a0);
                a1 = fmaf((float)hb1[7], wob1.w, a1);
                a2 = fmaf((float)hb2[7], woc1.w, a2);
                float acc = a0 + a1 + a2;             // this lane's 24 terms
                acc += __shfl_xor(acc, 32, 64);       // quad ^2
                acc += __shfl_xor(acc, 16, 64);       // quad ^1 -> full dot
                if ((lane == 0 || lane == 8) && it > 0)
                    y_buf[bsub][((it - 1) >> 7) & 1][(it - 1) & (CHUNK - 1)] =
                        acc + bout;
            }
            // ring flush: chunk [it-1-CHUNK, it-1) complete
            if ((it & (CHUNK - 1)) == 1 && it > 1) {
                const int base = it - 1 - CHUNK;
                const int pb   = (base >> 7) & 1;
                const int bsel = lane >> 5;
                const int li   = lane & 31;
                const f32x4 v =
                    *reinterpret_cast<const f32x4*>(&y_buf[bsel][pb][li * 4]);
                float* yrow = y + (size_t)(2 * blockIdx.x + bsel) * T_LEN;
                *reinterpret_cast<f32x4*>(&yrow[base + li * 4]) = v;
            }
        }
        __syncthreads();  // h_s[p^1] + y_buf ready (9-wave barrier)
    }
}

extern "C" void kernel_launch(void* const* d_in, const int* in_sizes, int n_in,
                              void* d_out, int out_size, void* d_ws, size_t ws_size,
                              hipStream_t stream) {
    const float* x     = (const float*)d_in[0];
    const float* w_ih  = (const float*)d_in[1];
    const float* w_hh  = (const float*)d_in[2];
    const float* b_ih  = (const float*)d_in[3];
    const float* b_hh  = (const float*)d_in[4];
    const float* w_out = (const float*)d_in[5];
    const float* b_out = (const float*)d_in[6];
    float* y = (float*)d_out;

    const int NBLK = 64;  // 2 batches per block (packed into B columns)
    lstm_mfma18_kernel<<<dim3(NBLK), dim3(NTHR), 0, stream>>>(
        x, w_ih, w_hh, b_ih, b_hh, w_out, b_out, y);
}

// Round 6
// 2923.893 us; speedup vs baseline: 1.3053x; 1.2151x over previous
//
#include <hip/hip_runtime.h>

// SimpleLSTM B=128,T=8192,H=96. R19 = R15 (best, 3059us) + serial-chain
// shaves. Consolidated model (R14-R18): per-CU MFMAs/step is FIXED at 72
// (N-columns are batch-invariant waste) -> per-SIMD pipe ~370 cyc is a hard
// floor; R18 proved wave-splitting can't cut it and only adds LDS-burst +
// barrier-skew. R15 step = 895 cyc vs ~710 floor; the slack is small serial
// items. R19 shaves: (1) x chunk-prefetch -- one f32x4 per 4 steps
// (unroll-4, compile-time parity), removing 3/4 of per-step x LDS ops from
// the post-barrier burst; (2) c'-domain fold -- carry cs=2log2e*c so the
// h-path is exp2(cs) directly (deletes one v_mul from the critical chain);
// g-gate emits gg2=2log2e*tanh(pre) at identical op count; (3) explicit
// xb=fmaf(x,wih,bias) hoisted before the MFMA block (post-select work = one
// add per gate). Keep: 5 waves (4 gate + y/flush VALU wave), 2 batches in
// B cols, permuted W rows, exp2 prescale, named scalars, pinned A-frags,
// all-lane h write, y ring flush by 128, setprio(1) on gate waves.

#define T_LEN 8192
#define H_DIM 96
#define NTHR  320   // 5 waves: 4 gate waves + 1 y/flush wave
#define CHUNK 128
#define LOG2E 1.44269504f

typedef float    f32x4 __attribute__((ext_vector_type(4)));
typedef _Float16 half8 __attribute__((ext_vector_type(8)));

#define MFMA16(A, B, C)                                                        \
    __builtin_amdgcn_mfma_f32_16x16x32_f16(__builtin_bit_cast(half8, (A)),     \
                                           __builtin_bit_cast(half8, (B)),     \
                                           (C), 0, 0, 0)

__device__ __forceinline__ float sig2(float s) {   // sigmoid, s = log2e*pre
    return __builtin_amdgcn_rcpf(1.0f + __builtin_amdgcn_exp2f(-s));
}

__device__ __forceinline__ f32x4 load_afrag(const float* __restrict__ w_hh,
                                            int mt, int kt, int m, int quad) {
    half8 f;
    const int r = m & 3;                       // gate: 0=i 1=f 2=g 3=o
    const float scale = (r == 2) ? 2.0f * LOG2E : LOG2E;
    const int orig = r * 96 + 4 * mt + (m >> 2);
    const float* src = w_hh + orig * H_DIM + kt * 32 + quad * 8;
    #pragma unroll
    for (int jj = 0; jj < 8; ++jj) f[jj] = (_Float16)(scale * src[jj]);
    return __builtin_bit_cast(f32x4, f);
}

__global__ __launch_bounds__(NTHR, 2) void lstm_mfma19_kernel(
    const float* __restrict__ x,      // [B, T]
    const float* __restrict__ w_ih,   // [4H]
    const float* __restrict__ w_hh,   // [4H, H]
    const float* __restrict__ b_ih,   // [4H]
    const float* __restrict__ b_hh,   // [4H]
    const float* __restrict__ w_out,  // [H]
    const float* __restrict__ b_out,  // [1]
    float* __restrict__ y)            // [B, T]
{
    const int tid  = threadIdx.x;
    const int wv   = tid >> 6;        // wave 0..3 = gates, 4 = y/flush
    const int lane = tid & 63;
    const int m    = lane & 15;       // A-row / D-column index
    const int quad = lane >> 4;       // D row group / B K-chunk
    const int cc   = m & 7;           // within-batch column
    const int bsub = m >> 3;          // 0: batch 2b, 1: batch 2b+1

    __shared__ __align__(16) _Float16 h_s[2][2][H_DIM];       // [buf][bsub][cell]
    __shared__ __align__(16) float    y_buf[2][2][CHUNK];     // [bsub][ring][i]
    __shared__ __align__(16) float    x_s[2][T_LEN + 8];      // +8 pad: bank-split

    // ---- stage both batches' x into LDS
    {
        const float* xpair = x + (size_t)(2 * blockIdx.x) * T_LEN;
        for (int i = tid * 4; i < T_LEN; i += NTHR * 4) {
            *reinterpret_cast<f32x4*>(&x_s[0][i]) =
                *reinterpret_cast<const f32x4*>(&xpair[i]);
            *reinterpret_cast<f32x4*>(&x_s[1][i]) =
                *reinterpret_cast<const f32x4*>(&xpair[T_LEN + i]);
        }
    }

    // ---- A fragments (named, pinned). Gate wave wv owns tiles 6wv..6wv+5.
    const int mt0 = (wv < 4) ? 6 * wv : 0;
    f32x4 af00 = load_afrag(w_hh, mt0 + 0, 0, m, quad);
    f32x4 af01 = load_afrag(w_hh, mt0 + 0, 1, m, quad);
    f32x4 af02 = load_afrag(w_hh, mt0 + 0, 2, m, quad);
    f32x4 af10 = load_afrag(w_hh, mt0 + 1, 0, m, quad);
    f32x4 af11 = load_afrag(w_hh, mt0 + 1, 1, m, quad);
    f32x4 af12 = load_afrag(w_hh, mt0 + 1, 2, m, quad);
    f32x4 af20 = load_afrag(w_hh, mt0 + 2, 0, m, quad);
    f32x4 af21 = load_afrag(w_hh, mt0 + 2, 1, m, quad);
    f32x4 af22 = load_afrag(w_hh, mt0 + 2, 2, m, quad);
    f32x4 af30 = load_afrag(w_hh, mt0 + 3, 0, m, quad);
    f32x4 af31 = load_afrag(w_hh, mt0 + 3, 1, m, quad);
    f32x4 af32 = load_afrag(w_hh, mt0 + 3, 2, m, quad);
    f32x4 af40 = load_afrag(w_hh, mt0 + 4, 0, m, quad);
    f32x4 af41 = load_afrag(w_hh, mt0 + 4, 1, m, quad);
    f32x4 af42 = load_afrag(w_hh, mt0 + 4, 2, m, quad);
    f32x4 af50 = load_afrag(w_hh, mt0 + 5, 0, m, quad);
    f32x4 af51 = load_afrag(w_hh, mt0 + 5, 1, m, quad);
    f32x4 af52 = load_afrag(w_hh, mt0 + 5, 2, m, quad);
    f32x4 zero4 = {0.f, 0.f, 0.f, 0.f};
    asm volatile("" : "+v"(af00), "+v"(af01), "+v"(af02), "+v"(af10),
                      "+v"(af11), "+v"(af12), "+v"(af20));
    asm volatile("" : "+v"(af21), "+v"(af22), "+v"(af30), "+v"(af31),
                      "+v"(af32), "+v"(af40), "+v"(af41));
    asm volatile("" : "+v"(af42), "+v"(af50), "+v"(af51), "+v"(af52),
                      "+v"(zero4));

    // ---- y-wave only: w_out slices matching the B-frag k-positions (f32)
    f32x4 woa0 = {0,0,0,0}, woa1 = {0,0,0,0}, wob0 = {0,0,0,0},
          wob1 = {0,0,0,0}, woc0 = {0,0,0,0}, woc1 = {0,0,0,0};
    if (wv == 4) {
        woa0 = *reinterpret_cast<const f32x4*>(&w_out[quad * 8]);
        woa1 = *reinterpret_cast<const f32x4*>(&w_out[quad * 8 + 4]);
        wob0 = *reinterpret_cast<const f32x4*>(&w_out[32 + quad * 8]);
        wob1 = *reinterpret_cast<const f32x4*>(&w_out[32 + quad * 8 + 4]);
        woc0 = *reinterpret_cast<const f32x4*>(&w_out[64 + quad * 8]);
        woc1 = *reinterpret_cast<const f32x4*>(&w_out[64 + quad * 8 + 4]);
    }

    // ---- per-lane cell params (gate waves; exp2-domain prescaled)
    const int sel  = (cc >= 6) ? (cc - 6) : cc;
    const int cell = (wv < 4) ? (24 * wv + 4 * sel + quad) : 0;
    const bool s_b0 = sel & 1;
    const bool s_b1 = (sel >> 1) & 1;
    const bool s_b2 = (sel >> 2) & 1;
    const float bias_i = LOG2E * (b_ih[0 * H_DIM + cell] + b_hh[0 * H_DIM + cell]);
    const float bias_f = LOG2E * (b_ih[1 * H_DIM + cell] + b_hh[1 * H_DIM + cell]);
    const float bias_g = 2.0f * LOG2E * (b_ih[2 * H_DIM + cell] + b_hh[2 * H_DIM + cell]);
    const float bias_o = LOG2E * (b_ih[3 * H_DIM + cell] + b_hh[3 * H_DIM + cell]);
    const float wih_i  = LOG2E * w_ih[0 * H_DIM + cell];
    const float wih_f  = LOG2E * w_ih[1 * H_DIM + cell];
    const float wih_g  = 2.0f * LOG2E * w_ih[2 * H_DIM + cell];
    const float wih_o  = LOG2E * w_ih[3 * H_DIM + cell];
    const float bout   = b_out[0];
    float cs = 0.f;                   // cs = 2*log2e * c  (c'-domain state)
    if (tid < 2 * H_DIM) (&h_s[0][0][0])[tid] = (_Float16)0.0f;  // buf 0
    __syncthreads();

    if (wv < 4) __builtin_amdgcn_s_setprio(1);  // gates win SIMD0 arbitration

    // main loop in chunks of 4 steps; parity compile-time inside the chunk
    for (int it0 = 0; it0 < T_LEN; it0 += 4) {
        f32x4 xv = {0.f, 0.f, 0.f, 0.f};
        if (wv < 4)  // x[it0..it0+3] for this lane's batch, one b128 read
            xv = *reinterpret_cast<const f32x4*>(&x_s[bsub][it0]);

        #pragma unroll
        for (int u = 0; u < 4; ++u) {
            const int it = it0 + u;
            const int p = u & 1;      // == it & 1 (it0 multiple of 4)

            if (wv < 4) {
                // ------------- gate wave -------------
                const f32x4 b0 = *reinterpret_cast<const f32x4*>(&h_s[p][bsub][quad * 8]);
                const f32x4 b1 = *reinterpret_cast<const f32x4*>(&h_s[p][bsub][32 + quad * 8]);
                const f32x4 b2 = *reinterpret_cast<const f32x4*>(&h_s[p][bsub][64 + quad * 8]);
                const float x_cur = (u == 0) ? xv.x
                                  : (u == 1) ? xv.y
                                  : (u == 2) ? xv.z : xv.w;
                // hoisted x contribution (independent of MFMA results)
                const float xb_i = fmaf(x_cur, wih_i, bias_i);
                const float xb_f = fmaf(x_cur, wih_f, bias_f);
                const float xb_g = fmaf(x_cur, wih_g, bias_g);
                const float xb_o = fmaf(x_cur, wih_o, bias_o);

                f32x4 acc0 = MFMA16(af00, b0, zero4);
                f32x4 acc1 = MFMA16(af10, b0, zero4);
                f32x4 acc2 = MFMA16(af20, b0, zero4);
                f32x4 acc3 = MFMA16(af30, b0, zero4);
                f32x4 acc4 = MFMA16(af40, b0, zero4);
                f32x4 acc5 = MFMA16(af50, b0, zero4);
                acc0 = MFMA16(af01, b1, acc0);
                acc1 = MFMA16(af11, b1, acc1);
                acc2 = MFMA16(af21, b1, acc2);
                acc3 = MFMA16(af31, b1, acc3);
                acc4 = MFMA16(af41, b1, acc4);
                acc5 = MFMA16(af51, b1, acc5);
                acc0 = MFMA16(af02, b2, acc0);
                acc1 = MFMA16(af12, b2, acc1);
                acc2 = MFMA16(af22, b2, acc2);
                acc3 = MFMA16(af32, b2, acc3);
                acc4 = MFMA16(af42, b2, acc4);
                acc5 = MFMA16(af52, b2, acc5);

                // depth-3 binary select
                const f32x4 t0 = s_b0 ? acc1 : acc0;
                const f32x4 t1 = s_b0 ? acc3 : acc2;
                const f32x4 t2 = s_b0 ? acc5 : acc4;
                const f32x4 g4 = s_b2 ? t2 : (s_b1 ? t1 : t0);

                const float s0 = g4.x + xb_i;
                const float s1 = g4.y + xb_f;
                const float s2 = g4.z + xb_g;          // = 2log2e * pre_g
                const float s3 = g4.w + xb_o;
                const float ig = sig2(s0);
                const float fg = sig2(s1);
                const float og = sig2(s3);
                // gg2 = 2log2e * tanh(pre_g), same op count as tanh2
                const float rg = __builtin_amdgcn_rcpf(1.0f + __builtin_amdgcn_exp2f(s2));
                const float gg2 = fmaf(-4.0f * LOG2E, rg, 2.0f * LOG2E);
                cs = fmaf(fg, cs, ig * gg2);           // cs = 2log2e * c
                // h = og * tanh(c): exp2(cs) directly (no mul on this path)
                const float rc = __builtin_amdgcn_rcpf(1.0f + __builtin_amdgcn_exp2f(cs));
                const float th = fmaf(-2.0f, rc, 1.0f);
                const float h  = og * th;
                // all 64 lanes write; cc=6,7 bitwise-duplicate cc=0,1 (benign)
                h_s[p ^ 1][bsub][cell] = (_Float16)h;
            } else {
                // ------------- y / flush wave (VALU only) -------------
                const f32x4 b0 = *reinterpret_cast<const f32x4*>(&h_s[p][bsub][quad * 8]);
                const f32x4 b1 = *reinterpret_cast<const f32x4*>(&h_s[p][bsub][32 + quad * 8]);
                const f32x4 b2 = *reinterpret_cast<const f32x4*>(&h_s[p][bsub][64 + quad * 8]);
                const half8 hb0 = __builtin_bit_cast(half8, b0);
                const half8 hb1 = __builtin_bit_cast(half8, b1);
                const half8 hb2 = __builtin_bit_cast(half8, b2);
                float a0 = 0.f, a1 = 0.f, a2 = 0.f;   // 3 parallel chains
                #pragma unroll
                for (int j = 0; j < 4; ++j) {
                    a0 = fmaf((float)hb0[j], woa0[j], a0);
                    a1 = fmaf((float)hb1[j], wob0[j], a1);
                    a2 = fmaf((float)hb2[j], woc0[j], a2);
                }
                #pragma unroll
                for (int j = 0; j < 4; ++j) {
                    a0 = fmaf((float)hb0[4 + j], woa1[j], a0);
                    a1 = fmaf((float)hb1[4 + j], wob1[j], a1);
                    a2 = fmaf((float)hb2[4 + j], woc1[j], a2);
                }
                float acc = a0 + a1 + a2;             // this lane's 24 terms
                acc += __shfl_xor(acc, 32, 64);       // quad ^2
                acc += __shfl_xor(acc, 16, 64);       // quad ^1 -> full dot
                if ((lane == 0 || lane == 8) && it > 0)
                    y_buf[bsub][((it - 1) >> 7) & 1][(it - 1) & (CHUNK - 1)] =
                        acc + bout;
                // ring flush: at it = k*128 + 1 (k>=1), chunk [it-1-128, it-1)
                if (u == 1 && (it0 & (CHUNK - 1)) == 0 && it0 > 0) {
                    const int base = it0 - CHUNK;
                    const int pb   = (base >> 7) & 1;
                    const int bsel = lane >> 5;
                    const int li   = lane & 31;
                    const f32x4 v =
                        *reinterpret_cast<const f32x4*>(&y_buf[bsel][pb][li * 4]);
                    float* yrow = y + (size_t)(2 * blockIdx.x + bsel) * T_LEN;
                    *reinterpret_cast<f32x4*>(&yrow[base + li * 4]) = v;
                }
            }
            __syncthreads();  // h_s[p^1] + y_buf ready (5-wave barrier)
        }
    }

    // ---- epilogue: y_{T-1} + final ring flush
    if (wv == 4) {
        // h_{T-1} is in h_s[0] (T_LEN even)
        const f32x4 b0 = *reinterpret_cast<const f32x4*>(&h_s[0][bsub][quad * 8]);
        const f32x4 b1 = *reinterpret_cast<const f32x4*>(&h_s[0][bsub][32 + quad * 8]);
        const f32x4 b2 = *reinterpret_cast<const f32x4*>(&h_s[0][bsub][64 + quad * 8]);
        const half8 hb0 = __builtin_bit_cast(half8, b0);
        const half8 hb1 = __builtin_bit_cast(half8, b1);
        const half8 hb2 = __builtin_bit_cast(half8, b2);
        float a0 = 0.f, a1 = 0.f, a2 = 0.f;
        #pragma unroll
        for (int j = 0; j < 4; ++j) {
            a0 = fmaf((float)hb0[j], woa0[j], a0);
            a1 = fmaf((float)hb1[j], wob0[j], a1);
            a2 = fmaf((float)hb2[j], woc0[j], a2);
        }
        #pragma unroll
        for (int j = 0; j < 4; ++j) {
            a0 = fmaf((float)hb0[4 + j], woa1[j], a0);
            a1 = fmaf((float)hb1[4 + j], wob1[j], a1);
            a2 = fmaf((float)hb2[4 + j], woc1[j], a2);
        }
        float acc = a0 + a1 + a2;
        acc += __shfl_xor(acc, 32, 64);
        acc += __shfl_xor(acc, 16, 64);
        if (lane == 0 || lane == 8)
            y_buf[bsub][((T_LEN - 1) >> 7) & 1][(T_LEN - 1) & (CHUNK - 1)] =
                acc + bout;
    }
    __syncthreads();
    if (wv == 4) {  // flush last chunk [T_LEN-CHUNK, T_LEN)
        const int base = T_LEN - CHUNK;
        const int pb   = (base >> 7) & 1;
        const int bsel = lane >> 5;
        const int li   = lane & 31;
        const f32x4 v = *reinterpret_cast<const f32x4*>(&y_buf[bsel][pb][li * 4]);
        float* yrow = y + (size_t)(2 * blockIdx.x + bsel) * T_LEN;
        *reinterpret_cast<f32x4*>(&yrow[base + li * 4]) = v;
    }
}

extern "C" void kernel_launch(void* const* d_in, const int* in_sizes, int n_in,
                              void* d_out, int out_size, void* d_ws, size_t ws_size,
                              hipStream_t stream) {
    const float* x     = (const float*)d_in[0];
    const float* w_ih  = (const float*)d_in[1];
    const float* w_hh  = (const float*)d_in[2];
    const float* b_ih  = (const float*)d_in[3];
    const float* b_hh  = (const float*)d_in[4];
    const float* w_out = (const float*)d_in[5];
    const float* b_out = (const float*)d_in[6];
    float* y = (float*)d_out;

    const int NBLK = 64;  // 2 batches per block (packed into B columns)
    lstm_mfma19_kernel<<<dim3(NBLK), dim3(NTHR), 0, stream>>>(
        x, w_ih, w_hh, b_ih, b_hh, w_out, b_out, y);
}

// Round 7
// 2875.338 us; speedup vs baseline: 1.3274x; 1.0169x over previous
//
#include <hip/hip_runtime.h>

// SimpleLSTM B=128,T=8192,H=96. R20 = R19 (best, 2924us) + rcp-fusion.
// R19 counters (per-active-SIMD): MFMA busy ~291 cyc/step, VALU issue ~360,
// read ~120, barrier ~60-100 -- all serial within the gate wave. VALU is
// the largest term; ~160 cyc is the 10 quarter-rate trans ops (5 exp2 +
// 5 rcp). R20 fuses rcps through products the LSTM takes anyway (exact
// algebra, no approximation):
//   i*g:  u=2^s2, v=2^-s0: ig*gg2 = 2L(u-1) * rcp((u+1)(1+v))  [2 rcp -> 1]
//   h=o*tanh(c): w=2^cs, z=2^-s3: h = (w-1) * rcp((w+1)(1+z))  [2 rcp -> 1]
// Trans 10 -> 8 (5 exp2 + 3 rcp), ~-32 issue cyc, chain ~equal. Structural
// options re-examined & rejected: ping-pong role-split waves (window still
// carries full 72-MFMA/CU pipe but advances one pair -> 2x latency);
// 4-batch packing (per-CU MFMA invariant at 72, R18); poly sigmoids
// (errors compound through the 8192-step c recurrence). Carried from R19:
// 5 waves (4 gate + y/flush VALU wave), 2 batches in B cols, permuted W
// rows, exp2 prescale, x chunk-prefetch (f32x4 per 4 steps, compile-time
// parity), c'-domain state cs=2L*c, hoisted xb, named scalars, pinned
// A-frags, all-lane h write, y ring flush by 128, setprio(1) on gates.

#define T_LEN 8192
#define H_DIM 96
#define NTHR  320   // 5 waves: 4 gate waves + 1 y/flush wave
#define CHUNK 128
#define LOG2E 1.44269504f

typedef float    f32x4 __attribute__((ext_vector_type(4)));
typedef _Float16 half8 __attribute__((ext_vector_type(8)));

#define MFMA16(A, B, C)                                                        \
    __builtin_amdgcn_mfma_f32_16x16x32_f16(__builtin_bit_cast(half8, (A)),     \
                                           __builtin_bit_cast(half8, (B)),     \
                                           (C), 0, 0, 0)

__device__ __forceinline__ float sig2(float s) {   // sigmoid, s = log2e*pre
    return __builtin_amdgcn_rcpf(1.0f + __builtin_amdgcn_exp2f(-s));
}

__device__ __forceinline__ f32x4 load_afrag(const float* __restrict__ w_hh,
                                            int mt, int kt, int m, int quad) {
    half8 f;
    const int r = m & 3;                       // gate: 0=i 1=f 2=g 3=o
    const float scale = (r == 2) ? 2.0f * LOG2E : LOG2E;
    const int orig = r * 96 + 4 * mt + (m >> 2);
    const float* src = w_hh + orig * H_DIM + kt * 32 + quad * 8;
    #pragma unroll
    for (int jj = 0; jj < 8; ++jj) f[jj] = (_Float16)(scale * src[jj]);
    return __builtin_bit_cast(f32x4, f);
}

__global__ __launch_bounds__(NTHR, 2) void lstm_mfma20_kernel(
    const float* __restrict__ x,      // [B, T]
    const float* __restrict__ w_ih,   // [4H]
    const float* __restrict__ w_hh,   // [4H, H]
    const float* __restrict__ b_ih,   // [4H]
    const float* __restrict__ b_hh,   // [4H]
    const float* __restrict__ w_out,  // [H]
    const float* __restrict__ b_out,  // [1]
    float* __restrict__ y)            // [B, T]
{
    const int tid  = threadIdx.x;
    const int wv   = tid >> 6;        // wave 0..3 = gates, 4 = y/flush
    const int lane = tid & 63;
    const int m    = lane & 15;       // A-row / D-column index
    const int quad = lane >> 4;       // D row group / B K-chunk
    const int cc   = m & 7;           // within-batch column
    const int bsub = m >> 3;          // 0: batch 2b, 1: batch 2b+1

    __shared__ __align__(16) _Float16 h_s[2][2][H_DIM];       // [buf][bsub][cell]
    __shared__ __align__(16) float    y_buf[2][2][CHUNK];     // [bsub][ring][i]
    __shared__ __align__(16) float    x_s[2][T_LEN + 8];      // +8 pad: bank-split

    // ---- stage both batches' x into LDS
    {
        const float* xpair = x + (size_t)(2 * blockIdx.x) * T_LEN;
        for (int i = tid * 4; i < T_LEN; i += NTHR * 4) {
            *reinterpret_cast<f32x4*>(&x_s[0][i]) =
                *reinterpret_cast<const f32x4*>(&xpair[i]);
            *reinterpret_cast<f32x4*>(&x_s[1][i]) =
                *reinterpret_cast<const f32x4*>(&xpair[T_LEN + i]);
        }
    }

    // ---- A fragments (named, pinned). Gate wave wv owns tiles 6wv..6wv+5.
    const int mt0 = (wv < 4) ? 6 * wv : 0;
    f32x4 af00 = load_afrag(w_hh, mt0 + 0, 0, m, quad);
    f32x4 af01 = load_afrag(w_hh, mt0 + 0, 1, m, quad);
    f32x4 af02 = load_afrag(w_hh, mt0 + 0, 2, m, quad);
    f32x4 af10 = load_afrag(w_hh, mt0 + 1, 0, m, quad);
    f32x4 af11 = load_afrag(w_hh, mt0 + 1, 1, m, quad);
    f32x4 af12 = load_afrag(w_hh, mt0 + 1, 2, m, quad);
    f32x4 af20 = load_afrag(w_hh, mt0 + 2, 0, m, quad);
    f32x4 af21 = load_afrag(w_hh, mt0 + 2, 1, m, quad);
    f32x4 af22 = load_afrag(w_hh, mt0 + 2, 2, m, quad);
    f32x4 af30 = load_afrag(w_hh, mt0 + 3, 0, m, quad);
    f32x4 af31 = load_afrag(w_hh, mt0 + 3, 1, m, quad);
    f32x4 af32 = load_afrag(w_hh, mt0 + 3, 2, m, quad);
    f32x4 af40 = load_afrag(w_hh, mt0 + 4, 0, m, quad);
    f32x4 af41 = load_afrag(w_hh, mt0 + 4, 1, m, quad);
    f32x4 af42 = load_afrag(w_hh, mt0 + 4, 2, m, quad);
    f32x4 af50 = load_afrag(w_hh, mt0 + 5, 0, m, quad);
    f32x4 af51 = load_afrag(w_hh, mt0 + 5, 1, m, quad);
    f32x4 af52 = load_afrag(w_hh, mt0 + 5, 2, m, quad);
    f32x4 zero4 = {0.f, 0.f, 0.f, 0.f};
    asm volatile("" : "+v"(af00), "+v"(af01), "+v"(af02), "+v"(af10),
                      "+v"(af11), "+v"(af12), "+v"(af20));
    asm volatile("" : "+v"(af21), "+v"(af22), "+v"(af30), "+v"(af31),
                      "+v"(af32), "+v"(af40), "+v"(af41));
    asm volatile("" : "+v"(af42), "+v"(af50), "+v"(af51), "+v"(af52),
                      "+v"(zero4));

    // ---- y-wave only: w_out slices matching the B-frag k-positions (f32)
    f32x4 woa0 = {0,0,0,0}, woa1 = {0,0,0,0}, wob0 = {0,0,0,0},
          wob1 = {0,0,0,0}, woc0 = {0,0,0,0}, woc1 = {0,0,0,0};
    if (wv == 4) {
        woa0 = *reinterpret_cast<const f32x4*>(&w_out[quad * 8]);
        woa1 = *reinterpret_cast<const f32x4*>(&w_out[quad * 8 + 4]);
        wob0 = *reinterpret_cast<const f32x4*>(&w_out[32 + quad * 8]);
        wob1 = *reinterpret_cast<const f32x4*>(&w_out[32 + quad * 8 + 4]);
        woc0 = *reinterpret_cast<const f32x4*>(&w_out[64 + quad * 8]);
        woc1 = *reinterpret_cast<const f32x4*>(&w_out[64 + quad * 8 + 4]);
    }

    // ---- per-lane cell params (gate waves; exp2-domain prescaled)
    const int sel  = (cc >= 6) ? (cc - 6) : cc;
    const int cell = (wv < 4) ? (24 * wv + 4 * sel + quad) : 0;
    const bool s_b0 = sel & 1;
    const bool s_b1 = (sel >> 1) & 1;
    const bool s_b2 = (sel >> 2) & 1;
    const float bias_i = LOG2E * (b_ih[0 * H_DIM + cell] + b_hh[0 * H_DIM + cell]);
    const float bias_f = LOG2E * (b_ih[1 * H_DIM + cell] + b_hh[1 * H_DIM + cell]);
    const float bias_g = 2.0f * LOG2E * (b_ih[2 * H_DIM + cell] + b_hh[2 * H_DIM + cell]);
    const float bias_o = LOG2E * (b_ih[3 * H_DIM + cell] + b_hh[3 * H_DIM + cell]);
    const float wih_i  = LOG2E * w_ih[0 * H_DIM + cell];
    const float wih_f  = LOG2E * w_ih[1 * H_DIM + cell];
    const float wih_g  = 2.0f * LOG2E * w_ih[2 * H_DIM + cell];
    const float wih_o  = LOG2E * w_ih[3 * H_DIM + cell];
    const float bout   = b_out[0];
    float cs = 0.f;                   // cs = 2*log2e * c  (c'-domain state)
    if (tid < 2 * H_DIM) (&h_s[0][0][0])[tid] = (_Float16)0.0f;  // buf 0
    __syncthreads();

    if (wv < 4) __builtin_amdgcn_s_setprio(1);  // gates win SIMD0 arbitration

    // main loop in chunks of 4 steps; parity compile-time inside the chunk
    for (int it0 = 0; it0 < T_LEN; it0 += 4) {
        f32x4 xv = {0.f, 0.f, 0.f, 0.f};
        if (wv < 4)  // x[it0..it0+3] for this lane's batch, one b128 read
            xv = *reinterpret_cast<const f32x4*>(&x_s[bsub][it0]);

        #pragma unroll
        for (int u4 = 0; u4 < 4; ++u4) {
            const int it = it0 + u4;
            const int p = u4 & 1;     // == it & 1 (it0 multiple of 4)

            if (wv < 4) {
                // ------------- gate wave -------------
                const f32x4 b0 = *reinterpret_cast<const f32x4*>(&h_s[p][bsub][quad * 8]);
                const f32x4 b1 = *reinterpret_cast<const f32x4*>(&h_s[p][bsub][32 + quad * 8]);
                const f32x4 b2 = *reinterpret_cast<const f32x4*>(&h_s[p][bsub][64 + quad * 8]);
                const float x_cur = (u4 == 0) ? xv.x
                                  : (u4 == 1) ? xv.y
                                  : (u4 == 2) ? xv.z : xv.w;
                // hoisted x contribution (independent of MFMA results)
                const float xb_i = fmaf(x_cur, wih_i, bias_i);
                const float xb_f = fmaf(x_cur, wih_f, bias_f);
                const float xb_g = fmaf(x_cur, wih_g, bias_g);
                const float xb_o = fmaf(x_cur, wih_o, bias_o);

                f32x4 acc0 = MFMA16(af00, b0, zero4);
                f32x4 acc1 = MFMA16(af10, b0, zero4);
                f32x4 acc2 = MFMA16(af20, b0, zero4);
                f32x4 acc3 = MFMA16(af30, b0, zero4);
                f32x4 acc4 = MFMA16(af40, b0, zero4);
                f32x4 acc5 = MFMA16(af50, b0, zero4);
                acc0 = MFMA16(af01, b1, acc0);
                acc1 = MFMA16(af11, b1, acc1);
                acc2 = MFMA16(af21, b1, acc2);
                acc3 = MFMA16(af31, b1, acc3);
                acc4 = MFMA16(af41, b1, acc4);
                acc5 = MFMA16(af51, b1, acc5);
                acc0 = MFMA16(af02, b2, acc0);
                acc1 = MFMA16(af12, b2, acc1);
                acc2 = MFMA16(af22, b2, acc2);
                acc3 = MFMA16(af32, b2, acc3);
                acc4 = MFMA16(af42, b2, acc4);
                acc5 = MFMA16(af52, b2, acc5);

                // depth-3 binary select
                const f32x4 t0 = s_b0 ? acc1 : acc0;
                const f32x4 t1 = s_b0 ? acc3 : acc2;
                const f32x4 t2 = s_b0 ? acc5 : acc4;
                const f32x4 g4 = s_b2 ? t2 : (s_b1 ? t1 : t0);

                const float s0 = g4.x + xb_i;          // = log2e * pre_i
                const float s1 = g4.y + xb_f;          // = log2e * pre_f
                const float s2 = g4.z + xb_g;          // = 2log2e * pre_g
                const float s3 = g4.w + xb_o;          // = log2e * pre_o
                // fused i*g: ig*gg2 = 2L(u-1) * rcp((u+1)(1+v))
                const float uu = __builtin_amdgcn_exp2f(s2);
                const float vv = __builtin_amdgcn_exp2f(-s0);
                const float fg = sig2(s1);
                const float zz = __builtin_amdgcn_exp2f(-s3);
                const float igg = fmaf(uu, 2.0f * LOG2E, -2.0f * LOG2E) *
                    __builtin_amdgcn_rcpf((uu + 1.0f) * (1.0f + vv));
                cs = fmaf(fg, cs, igg);                // cs = 2log2e * c
                // fused h = og*tanh(c) = (w-1) * rcp((w+1)(1+z))
                const float ww = __builtin_amdgcn_exp2f(cs);
                const float h  = (ww - 1.0f) *
                    __builtin_amdgcn_rcpf((ww + 1.0f) * (1.0f + zz));
                // all 64 lanes write; cc=6,7 bitwise-duplicate cc=0,1 (benign)
                h_s[p ^ 1][bsub][cell] = (_Float16)h;
            } else {
                // ------------- y / flush wave (VALU only) -------------
                const f32x4 b0 = *reinterpret_cast<const f32x4*>(&h_s[p][bsub][quad * 8]);
                const f32x4 b1 = *reinterpret_cast<const f32x4*>(&h_s[p][bsub][32 + quad * 8]);
                const f32x4 b2 = *reinterpret_cast<const f32x4*>(&h_s[p][bsub][64 + quad * 8]);
                const half8 hb0 = __builtin_bit_cast(half8, b0);
                const half8 hb1 = __builtin_bit_cast(half8, b1);
                const half8 hb2 = __builtin_bit_cast(half8, b2);
                float a0 = 0.f, a1 = 0.f, a2 = 0.f;   // 3 parallel chains
                #pragma unroll
                for (int j = 0; j < 4; ++j) {
                    a0 = fmaf((float)hb0[j], woa0[j], a0);
                    a1 = fmaf((float)hb1[j], wob0[j], a1);
                    a2 = fmaf((float)hb2[j], woc0[j], a2);
                }
                #pragma unroll
                for (int j = 0; j < 4; ++j) {
                    a0 = fmaf((float)hb0[4 + j], woa1[j], a0);
                    a1 = fmaf((float)hb1[4 + j], wob1[j], a1);
                    a2 = fmaf((float)hb2[4 + j], woc1[j], a2);
                }
                float acc = a0 + a1 + a2;             // this lane's 24 terms
                acc += __shfl_xor(acc, 32, 64);       // quad ^2
                acc += __shfl_xor(acc, 16, 64);       // quad ^1 -> full dot
                if ((lane == 0 || lane == 8) && it > 0)
                    y_buf[bsub][((it - 1) >> 7) & 1][(it - 1) & (CHUNK - 1)] =
                        acc + bout;
                // ring flush: at it = k*128 + 1 (k>=1), chunk [it-1-128, it-1)
                if (u4 == 1 && (it0 & (CHUNK - 1)) == 0 && it0 > 0) {
                    const int base = it0 - CHUNK;
                    const int pb   = (base >> 7) & 1;
                    const int bsel = lane >> 5;
                    const int li   = lane & 31;
                    const f32x4 v =
                        *reinterpret_cast<const f32x4*>(&y_buf[bsel][pb][li * 4]);
                    float* yrow = y + (size_t)(2 * blockIdx.x + bsel) * T_LEN;
                    *reinterpret_cast<f32x4*>(&yrow[base + li * 4]) = v;
                }
            }
            __syncthreads();  // h_s[p^1] + y_buf ready (5-wave barrier)
        }
    }

    // ---- epilogue: y_{T-1} + final ring flush
    if (wv == 4) {
        // h_{T-1} is in h_s[0] (T_LEN even)
        const f32x4 b0 = *reinterpret_cast<const f32x4*>(&h_s[0][bsub][quad * 8]);
        const f32x4 b1 = *reinterpret_cast<const f32x4*>(&h_s[0][bsub][32 + quad * 8]);
        const f32x4 b2 = *reinterpret_cast<const f32x4*>(&h_s[0][bsub][64 + quad * 8]);
        const half8 hb0 = __builtin_bit_cast(half8, b0);
        const half8 hb1 = __builtin_bit_cast(half8, b1);
        const half8 hb2 = __builtin_bit_cast(half8, b2);
        float a0 = 0.f, a1 = 0.f, a2 = 0.f;
        #pragma unroll
        for (int j = 0; j < 4; ++j) {
            a0 = fmaf((float)hb0[j], woa0[j], a0);
            a1 = fmaf((float)hb1[j], wob0[j], a1);
            a2 = fmaf((float)hb2[j], woc0[j], a2);
        }
        #pragma unroll
        for (int j = 0; j < 4; ++j) {
            a0 = fmaf((float)hb0[4 + j], woa1[j], a0);
            a1 = fmaf((float)hb1[4 + j], wob1[j], a1);
            a2 = fmaf((float)hb2[4 + j], woc1[j], a2);
        }
        float acc = a0 + a1 + a2;
        acc += __shfl_xor(acc, 32, 64);
        acc += __shfl_xor(acc, 16, 64);
        if (lane == 0 || lane == 8)
            y_buf[bsub][((T_LEN - 1) >> 7) & 1][(T_LEN - 1) & (CHUNK - 1)] =
                acc + bout;
    }
    __syncthreads();
    if (wv == 4) {  // flush last chunk [T_LEN-CHUNK, T_LEN)
        const int base = T_LEN - CHUNK;
        const int pb   = (base >> 7) & 1;
        const int bsel = lane >> 5;
        const int li   = lane & 31;
        const f32x4 v = *reinterpret_cast<const f32x4*>(&y_buf[bsel][pb][li * 4]);
        float* yrow = y + (size_t)(2 * blockIdx.x + bsel) * T_LEN;
        *reinterpret_cast<f32x4*>(&yrow[base + li * 4]) = v;
    }
}

extern "C" void kernel_launch(void* const* d_in, const int* in_sizes, int n_in,
                              void* d_out, int out_size, void* d_ws, size_t ws_size,
                              hipStream_t stream) {
    const float* x     = (const float*)d_in[0];
    const float* w_ih  = (const float*)d_in[1];
    const float* w_hh  = (const float*)d_in[2];
    const float* b_ih  = (const float*)d_in[3];
    const float* b_hh  = (const float*)d_in[4];
    const float* w_out = (const float*)d_in[5];
    const float* b_out = (const float*)d_in[6];
    float* y = (float*)d_out;

    const int NBLK = 64;  // 2 batches per block (packed into B columns)
    lstm_mfma20_kernel<<<dim3(NBLK), dim3(NTHR), 0, stream>>>(
        x, w_ih, w_hh, b_ih, b_hh, w_out, b_out, y);
}